// Round 5
// baseline (560.415 us; speedup 1.0000x reference)
//
#include <hip/hip_runtime.h>
#include <stdint.h>

// Batched tiny MLP [B,13]->16->(30x 16->16 relu)->1, fp32 in/out, bf16 MFMA.
// Transposed formulation: mfma_f32_16x16x16_bf16 D layout == B layout, so each
// layer's relu'd output is the next layer's B fragment in-register.
// R5: 100%-occupancy build (8 waves/SIMD). x staged by global_load_lds (async
// DMA, no staging VGPRs) into a wave-private LDS buffer; per-layer weights and
// biases streamed from global (coalesced, L2-hot) with a one-layer-ahead
// register pipeline. <=64 VGPRs target; 13 KB LDS; 2048 blocks = 8/CU.

typedef __attribute__((ext_vector_type(4))) short short4v;
typedef __attribute__((ext_vector_type(4))) float float4v;

#define S_IN 13
#define H 16
#define NL 32            // mfma layers: 0 = input, 1..30 = hidden, 31 = output
#define TPB 256
#define WPB 4            // waves per block
#define T 4              // 16-sample tiles per wave per iteration
#define NBLOCKS 2048     // 8 blocks/CU on 256 CUs
#define STRIDE (NBLOCKS * WPB * T)   // tiles per grid sweep = 32768

// per-wave LDS: 832 x dwords + 4 zero pad = 836 dwords
#define XS_DW 836

__device__ __forceinline__ unsigned pk_bf16(float a, float b) {
#if __has_builtin(__builtin_amdgcn_cvt_pk_bf16_f32)
    typedef __attribute__((ext_vector_type(2))) __bf16 bf16x2;
    bf16x2 v = __builtin_amdgcn_cvt_pk_bf16_f32(a, b);
    return __builtin_bit_cast(unsigned, v);
#else
    unsigned ra = __float_as_uint(a), rb = __float_as_uint(b);
    ra += 0x7fffu + ((ra >> 16) & 1u);
    rb += 0x7fffu + ((rb >> 16) & 1u);
    return __builtin_amdgcn_perm(rb, ra, 0x07060302u);
#endif
}

__device__ __forceinline__ short4v pack4(float v0, float v1, float v2, float v3) {
    int2 p;
    p.x = (int)pk_bf16(v0, v1);
    p.y = (int)pk_bf16(v2, v3);
    return __builtin_bit_cast(short4v, p);
}

__device__ __forceinline__ float4v ld16u(const float* p) {
    float4v v;
    __builtin_memcpy(&v, p, 16);
    return v;
}

// async global->LDS DMA: per-lane global addr, wave-uniform LDS base,
// lane i lands at ldsbase + i*size.
__device__ __forceinline__ void cp16(const float* g, unsigned* l) {
    __builtin_amdgcn_global_load_lds(
        (const __attribute__((address_space(1))) unsigned*)g,
        (__attribute__((address_space(3))) unsigned*)l, 16, 0, 0);
}
__device__ __forceinline__ void cp4(const float* g, unsigned* l) {
    __builtin_amdgcn_global_load_lds(
        (const __attribute__((address_space(1))) unsigned*)g,
        (__attribute__((address_space(3))) unsigned*)l, 4, 0, 0);
}

__global__ __launch_bounds__(TPB, 8)
void mlp_kernel(const float* __restrict__ x,
                const float* __restrict__ W_in, const float* __restrict__ b_in,
                const float* __restrict__ W_h,  const float* __restrict__ b_h,
                const float* __restrict__ W_out,const float* __restrict__ b_out,
                float* __restrict__ out, int tiles)
{
    __shared__ unsigned xsAll[WPB * XS_DW];

    const int tid  = threadIdx.x;
    const int lane = tid & 63;
    const int wv   = tid >> 6;
    const int g    = lane >> 4;
    const int col  = lane & 15;        // sample within tile == A row m
    const int k0   = 4 * g;
    const bool g3  = (g == 3);

    unsigned* xs = xsAll + wv * XS_DW;         // wave-private staging
    if (lane < 4) xs[832 + lane] = 0;          // zero gather-overshoot pad

    // ---- pinned irregular-layer fragments (once per wave) ----
    short4v aF0, aOut;
    float4v c0;
    {
        const int offk = g3 ? 9 : k0;          // g3 loads k=9..12, keeps k=12
        float4v w = ld16u(W_in + col * S_IN + offk);
        float v0 = g3 ? w[3] : w[0];
        float v1 = g3 ? 0.f : w[1];
        float v2 = g3 ? 0.f : w[2];
        float v3 = g3 ? 0.f : w[3];
        aF0 = pack4(v0, v1, v2, v3);
    }
    {
        float4v w = ld16u(W_out + k0);
        if (col != 0) { w[0] = 0.f; w[1] = 0.f; w[2] = 0.f; w[3] = 0.f; }
        aOut = pack4(w[0], w[1], w[2], w[3]);
    }
    c0 = ld16u(b_in + k0);                     // bias frag rows 4g..4g+3
    const float bOut = *b_out;
    const float4v zf = {0.f, 0.f, 0.f, 0.f};

    const int wave_id = blockIdx.x * WPB + wv;
    int tb = wave_id * T;
    if (tb >= tiles) return;

    const float* xp = x + (size_t)tb * 208;    // 4 tiles = 832 dwords
    float* op = out + (size_t)tb * 16 + lane;

    // per-lane frag offsets for streamed W/bias
    const int wOff = col * 16 + k0;            // dwords into a 256-dword layer
    const int col13k = col * 13 + k0;

    // prologue: issue first iteration's x DMA (4 ops, 3328 B)
    cp16(xp + lane * 4,        xs);
    cp16(xp + 256 + lane * 4,  xs + 256);
    cp16(xp + 512 + lane * 4,  xs + 512);
    cp4 (xp + 768 + lane,      xs + 768);

    for (; tb < tiles; tb += STRIDE) {
        // wait for this iteration's DMA (drains stores too -- they're old)
        __builtin_amdgcn_s_waitcnt(0x0F70);    // vmcnt(0)

        // gather input-layer B fragments (stride-13 dword reads).
        // k slots 13..15 read neighbor x / zero pad: finite, and A there is 0.
        short4v bf[T];
#pragma unroll
        for (int t = 0; t < T; ++t) {
            const unsigned* p = xs + t * 208 + col13k;
            bf[t] = pack4(__uint_as_float(p[0]), __uint_as_float(p[1]),
                          __uint_as_float(p[2]), __uint_as_float(p[3]));
        }
        // reads complete before next DMA may overwrite the buffer
        __builtin_amdgcn_s_waitcnt(0xC07F);    // lgkmcnt(0)

        const int tbn = tb + STRIDE;
        if (tbn < tiles) {
            xp += (size_t)STRIDE * 208;
            cp16(xp + lane * 4,        xs);
            cp16(xp + 256 + lane * 4,  xs + 256);
            cp16(xp + 512 + lane * 4,  xs + 512);
            cp4 (xp + 768 + lane,      xs + 768);
        }

        // ---- 31 layers with one-layer-ahead W/bias register pipeline ----
        short4v aC = aF0;
        float4v cC = c0;
#pragma unroll
        for (int L = 0; L < NL - 1; ++L) {
            short4v aN;
            float4v cN;
            if (L < 30) {
                float4v w = ld16u(W_h + L * 256 + wOff);   // coalesced 1KB/wave
                aN = pack4(w[0], w[1], w[2], w[3]);
                cN = ld16u(b_h + L * 16 + k0);
            } else {
                aN = aOut;
                cN = zf;
            }
            float4v d[T];
#pragma unroll
            for (int t = 0; t < T; ++t)
                d[t] = __builtin_amdgcn_mfma_f32_16x16x16bf16_1k(aC, bf[t], cC, 0, 0, 0);
#pragma unroll
            for (int t = 0; t < T; ++t)
                bf[t] = pack4(fmaxf(d[t][0], 0.f), fmaxf(d[t][1], 0.f),
                              fmaxf(d[t][2], 0.f), fmaxf(d[t][3], 0.f));
            aC = aN;
            cC = cN;
        }

        // output layer: W_out lives in row 0 only; y[n] = D[0][n] + b_out
#pragma unroll
        for (int t = 0; t < T; ++t) {
            float4v d = __builtin_amdgcn_mfma_f32_16x16x16bf16_1k(aC, bf[t], cC, 0, 0, 0);
            if (lane < 16) op[t * 16] = d[0] + bOut;
        }
        op += (size_t)STRIDE * 16;
    }
}

extern "C" void kernel_launch(void* const* d_in, const int* in_sizes, int n_in,
                              void* d_out, int out_size, void* d_ws, size_t ws_size,
                              hipStream_t stream) {
    const float* x     = (const float*)d_in[0];
    const float* W_in  = (const float*)d_in[1];
    const float* b_in  = (const float*)d_in[2];
    const float* W_h   = (const float*)d_in[3];
    const float* b_h   = (const float*)d_in[4];
    const float* W_out = (const float*)d_in[5];
    const float* b_out = (const float*)d_in[6];
    float* out = (float*)d_out;

    const int tiles = out_size / 16;                       // 131072
    int blocks = (tiles + WPB * T - 1) / (WPB * T);
    if (blocks > NBLOCKS) blocks = NBLOCKS;
    mlp_kernel<<<blocks, TPB, 0, stream>>>(x, W_in, b_in, W_h, b_h, W_out, b_out,
                                           out, tiles);
}

// Round 7
// 234.707 us; speedup vs baseline: 2.3877x; 2.3877x over previous
//
#include <hip/hip_runtime.h>
#include <stdint.h>

// Batched tiny MLP [B,13]->16->(30x 16->16 relu)->1, fp32 in/out, f16 MFMA.
// Transposed formulation: mfma_f32_16x16x16_f16 D layout == B layout
// (row=(lane>>4)*4+reg == k=(lane>>4)*4+i, col==n==lane&15), so each layer's
// relu'd output is the next layer's B fragment with zero cross-lane movement.
// R7 (=R6 + compile fix): f16 path -- v_cvt_pkrtz_f16_f32 is a guaranteed
// single-instruction f32x2->f16x2 pack; f16 10-bit mantissa beats bf16.
// A-frags (f16, 16KB) + biases (2KB) in LDS, x staged per-wave (13.3KB)
// => 31.5KB/block = 5 blocks/CU; NBLOCKS=1280 fills them; launch_bounds(,5)
// caps VGPR at 102 so waves are LDS-limited, not VGPR-limited.

typedef __attribute__((ext_vector_type(4))) _Float16 half4v;
typedef __attribute__((ext_vector_type(4))) float float4v;

#define S_IN 13
#define H 16
#define NL 32            // mfma layers: 0 = input, 1..30 = hidden, 31 = output
#define TPB 256
#define WPB 4            // waves per block
#define T 4              // 16-sample tiles per wave per iteration
#define NBLOCKS 1280     // 5 blocks/CU * 256 CUs (LDS-limited residency)
#define STRIDE (NBLOCKS * WPB * T)   // tiles per grid sweep = 20480

// LDS dword map:
//   [0, 4096)            A-frags: 2 dwords (4 f16) per (L, lane)
//   [4096, 4608)         bias[L][m] fp32 (C-operand order)
//   [4608, 4608+WPB*832) per-wave x staging (4 tiles * 16 samples * 13 dw)
//   +4 zero pad (input-frag gather may overshoot by up to 3 dwords)
#define XS_BASE 4608
#define LDS_DW (XS_BASE + WPB * 832 + 4)

__device__ __forceinline__ unsigned pkh(float a, float b) {
    return __builtin_bit_cast(unsigned, __builtin_amdgcn_cvt_pkrtz(a, b));
}

__device__ __forceinline__ half4v pack4h(float v0, float v1, float v2, float v3) {
    int2 p;
    p.x = (int)pkh(v0, v1);
    p.y = (int)pkh(v2, v3);
    return __builtin_bit_cast(half4v, p);
}

__global__ __launch_bounds__(TPB, 5)
void mlp_kernel(const float* __restrict__ x,
                const float* __restrict__ W_in, const float* __restrict__ b_in,
                const float* __restrict__ W_h,  const float* __restrict__ b_h,
                const float* __restrict__ W_out,const float* __restrict__ b_out,
                float* __restrict__ out, int tiles)
{
    __shared__ unsigned lds[LDS_DW];
    const int tid = threadIdx.x;

    // ---- swizzle weights into f16 A-fragment layout in LDS (once/block) ----
    for (int s = tid; s < NL * 64; s += TPB) {
        const int L = s >> 6, ln = s & 63, m = ln & 15, gg = ln >> 4;
        float v[4];
#pragma unroll
        for (int i = 0; i < 4; ++i) {
            const int k = 4 * gg + i;
            if (L == 0)       v[i] = (k < S_IN) ? W_in[m * S_IN + k] : 0.f;
            else if (L <= 30) v[i] = W_h[(L - 1) * H * H + m * H + k];
            else              v[i] = (m == 0) ? W_out[k] : 0.f;
        }
        lds[s * 2]     = pkh(v[0], v[1]);
        lds[s * 2 + 1] = pkh(v[2], v[3]);
    }
    for (int s = tid; s < NL * H; s += TPB) {
        const int L = s >> 4, m = s & 15;
        float bv;
        if (L == 0)       bv = b_in[m];
        else if (L <= 30) bv = b_h[(L - 1) * H + m];
        else              bv = (m == 0) ? b_out[0] : 0.f;
        lds[4096 + s] = __float_as_uint(bv);
    }
    if (tid < 4) lds[XS_BASE + WPB * 832 + tid] = 0;   // zero overshoot pad
    __syncthreads();

    const half4v* lA = (const half4v*)lds;             // [NL*64], 8B elems
    const float4v* lB = (const float4v*)(lds + 4096);  // [NL*4]

    const int lane = tid & 63;
    const int wv   = tid >> 6;
    const int g    = lane >> 4;
    const int col  = lane & 15;
    const int k0   = 4 * g;
    const int col13k = col * 13 + k0;

    unsigned* xs = lds + XS_BASE + wv * 832;           // wave-private staging

    const int wave_id = blockIdx.x * WPB + wv;
    int tb = wave_id * T;
    if (tb >= tiles) return;

    float* op = out + (size_t)tb * 16 + lane;

    // prefetch first iteration's x block (4 tiles = 832 dwords, coalesced)
    const float* xp = x + (size_t)tb * 208;
    float4v r0 = *(const float4v*)(xp + lane * 4);
    float4v r1 = *(const float4v*)(xp + 256 + lane * 4);
    float4v r2 = *(const float4v*)(xp + 512 + lane * 4);
    float    r3 = xp[768 + lane];

    for (; tb < tiles; tb += STRIDE) {
        // stage current x block (wave-private: no barrier needed)
        *(float4v*)(xs + lane * 4)       = r0;
        *(float4v*)(xs + 256 + lane * 4) = r1;
        *(float4v*)(xs + 512 + lane * 4) = r2;
        xs[768 + lane] = __float_as_uint(r3);

        // issue next iteration's global loads (in flight across layer chain)
        const int tbn = tb + STRIDE;
        if (tbn < tiles) {
            xp = x + (size_t)tbn * 208;
            r0 = *(const float4v*)(xp + lane * 4);
            r1 = *(const float4v*)(xp + 256 + lane * 4);
            r2 = *(const float4v*)(xp + 512 + lane * 4);
            r3 = xp[768 + lane];
        }

        // input-layer B fragments (stride-13 dword gather: conflict-free).
        // k slots 13..15 read neighbor x / zero pad: finite, A there is 0.
        half4v bf[T];
#pragma unroll
        for (int t = 0; t < T; ++t) {
            const unsigned* p = xs + t * 208 + col13k;
            bf[t] = pack4h(__uint_as_float(p[0]), __uint_as_float(p[1]),
                           __uint_as_float(p[2]), __uint_as_float(p[3]));
        }

        // ---- 31 layers, A/bias prefetched one ahead; bias rides in C ----
        half4v aC = lA[lane];          // layer 0
        float4v cC = lB[g];
#pragma unroll
        for (int L = 0; L < NL - 1; ++L) {
            const half4v aN = lA[(L + 1) * 64 + lane];
            const float4v cN = lB[(L + 1) * 4 + g];
            float4v d[T];
#pragma unroll
            for (int t = 0; t < T; ++t)
                d[t] = __builtin_amdgcn_mfma_f32_16x16x16f16(aC, bf[t], cC, 0, 0, 0);
#pragma unroll
            for (int t = 0; t < T; ++t)
                bf[t] = pack4h(fmaxf(d[t][0], 0.f), fmaxf(d[t][1], 0.f),
                               fmaxf(d[t][2], 0.f), fmaxf(d[t][3], 0.f));
            aC = aN;
            cC = cN;
        }

        // output layer: W_out lives in row 0 only; y[n] = D[0][n]
#pragma unroll
        for (int t = 0; t < T; ++t) {
            float4v d = __builtin_amdgcn_mfma_f32_16x16x16f16(aC, bf[t], cC, 0, 0, 0);
            if (lane < 16) op[t * 16] = d[0];
        }
        op += (size_t)STRIDE * 16;
    }
}

extern "C" void kernel_launch(void* const* d_in, const int* in_sizes, int n_in,
                              void* d_out, int out_size, void* d_ws, size_t ws_size,
                              hipStream_t stream) {
    const float* x     = (const float*)d_in[0];
    const float* W_in  = (const float*)d_in[1];
    const float* b_in  = (const float*)d_in[2];
    const float* W_h   = (const float*)d_in[3];
    const float* b_h   = (const float*)d_in[4];
    const float* W_out = (const float*)d_in[5];
    const float* b_out = (const float*)d_in[6];
    float* out = (float*)d_out;

    const int tiles = out_size / 16;                       // 131072
    int blocks = (tiles + WPB * T - 1) / (WPB * T);
    if (blocks > NBLOCKS) blocks = NBLOCKS;
    mlp_kernel<<<blocks, TPB, 0, stream>>>(x, W_in, b_in, W_h, b_h, W_out, b_out,
                                           out, tiles);
}

// Round 8
// 193.355 us; speedup vs baseline: 2.8984x; 1.2139x over previous
//
#include <hip/hip_runtime.h>
#include <stdint.h>

// Batched tiny MLP [B,13]->16->(30x 16->16 relu)->1, fp32 in/out, f16 MFMA.
// Transposed formulation: mfma_f32_16x16x16_f16 D layout == B layout
// (row=(lane>>4)*4+reg == k=(lane>>4)*4+i, col==n==lane&15), so each layer's
// relu'd output is the next layer's B fragment with zero cross-lane movement.
// R8: (1) relu done in f16 via v_pk_max_f16 AFTER cvt_pkrtz -- 4 VALU per
// tile-layer (2 cvt + 2 pkmax) vs 6; (2) TPB=512 so the 18KB weight/bias LDS
// is amortized over 8 waves: 45KB/block = 3 blocks/CU = 24 waves/CU (vs 20).

typedef __attribute__((ext_vector_type(4))) _Float16 half4v;
typedef __attribute__((ext_vector_type(2))) _Float16 h2;
typedef __attribute__((ext_vector_type(4))) float float4v;

#define S_IN 13
#define H 16
#define NL 32            // mfma layers: 0 = input, 1..30 = hidden, 31 = output
#define TPB 512
#define WPB 8            // waves per block
#define T 4              // 16-sample tiles per wave per iteration
#define NBLOCKS 768      // 3 blocks/CU * 256 CUs (LDS-limited residency)
#define STRIDE (NBLOCKS * WPB * T)   // tiles per grid sweep = 24576

// LDS dword map:
//   [0, 4096)            A-frags: 2 dwords (4 f16) per (L, lane)
//   [4096, 4608)         bias[L][m] fp32 (C-operand order)
//   [4608, 4608+WPB*832) per-wave x staging (4 tiles * 16 samples * 13 dw)
//   +4 zero pad (input-frag gather may overshoot by up to 3 dwords)
#define XS_BASE 4608
#define LDS_DW (XS_BASE + WPB * 832 + 4)

__device__ __forceinline__ unsigned pkh(float a, float b) {
    return __builtin_bit_cast(unsigned, __builtin_amdgcn_cvt_pkrtz(a, b));
}

__device__ __forceinline__ half4v pack4h(float v0, float v1, float v2, float v3) {
    int2 p;
    p.x = (int)pkh(v0, v1);
    p.y = (int)pkh(v2, v3);
    return __builtin_bit_cast(half4v, p);
}

// cvt then packed-f16 relu: 2 cvt + 2 v_pk_max_f16
__device__ __forceinline__ half4v relu_pack4h(const float4v& d) {
    const h2 z = {(_Float16)0.f, (_Float16)0.f};
    h2 lo = __builtin_bit_cast(h2, pkh(d[0], d[1]));
    h2 hi = __builtin_bit_cast(h2, pkh(d[2], d[3]));
    lo = __builtin_elementwise_max(lo, z);
    hi = __builtin_elementwise_max(hi, z);
    int2 p;
    p.x = __builtin_bit_cast(int, lo);
    p.y = __builtin_bit_cast(int, hi);
    return __builtin_bit_cast(half4v, p);
}

__global__ __launch_bounds__(TPB, 6)
void mlp_kernel(const float* __restrict__ x,
                const float* __restrict__ W_in, const float* __restrict__ b_in,
                const float* __restrict__ W_h,  const float* __restrict__ b_h,
                const float* __restrict__ W_out,const float* __restrict__ b_out,
                float* __restrict__ out, int tiles)
{
    __shared__ unsigned lds[LDS_DW];
    const int tid = threadIdx.x;

    // ---- swizzle weights into f16 A-fragment layout in LDS (once/block) ----
    for (int s = tid; s < NL * 64; s += TPB) {
        const int L = s >> 6, ln = s & 63, m = ln & 15, gg = ln >> 4;
        float v[4];
#pragma unroll
        for (int i = 0; i < 4; ++i) {
            const int k = 4 * gg + i;
            if (L == 0)       v[i] = (k < S_IN) ? W_in[m * S_IN + k] : 0.f;
            else if (L <= 30) v[i] = W_h[(L - 1) * H * H + m * H + k];
            else              v[i] = (m == 0) ? W_out[k] : 0.f;
        }
        lds[s * 2]     = pkh(v[0], v[1]);
        lds[s * 2 + 1] = pkh(v[2], v[3]);
    }
    for (int s = tid; s < NL * H; s += TPB) {
        const int L = s >> 4, m = s & 15;
        float bv;
        if (L == 0)       bv = b_in[m];
        else if (L <= 30) bv = b_h[(L - 1) * H + m];
        else              bv = (m == 0) ? b_out[0] : 0.f;
        lds[4096 + s] = __float_as_uint(bv);
    }
    if (tid < 4) lds[XS_BASE + WPB * 832 + tid] = 0;   // zero overshoot pad
    __syncthreads();

    const half4v* lA = (const half4v*)lds;             // [NL*64], 8B elems
    const float4v* lB = (const float4v*)(lds + 4096);  // [NL*4]

    const int lane = tid & 63;
    const int wv   = tid >> 6;
    const int g    = lane >> 4;
    const int col  = lane & 15;
    const int k0   = 4 * g;
    const int col13k = col * 13 + k0;

    unsigned* xs = lds + XS_BASE + wv * 832;           // wave-private staging

    const int wave_id = blockIdx.x * WPB + wv;
    int tb = wave_id * T;
    if (tb >= tiles) return;

    float* op = out + (size_t)tb * 16 + lane;

    // prefetch first iteration's x block (4 tiles = 832 dwords, coalesced)
    const float* xp = x + (size_t)tb * 208;
    float4v r0 = *(const float4v*)(xp + lane * 4);
    float4v r1 = *(const float4v*)(xp + 256 + lane * 4);
    float4v r2 = *(const float4v*)(xp + 512 + lane * 4);
    float    r3 = xp[768 + lane];

    for (; tb < tiles; tb += STRIDE) {
        // stage current x block (wave-private: no barrier needed)
        *(float4v*)(xs + lane * 4)       = r0;
        *(float4v*)(xs + 256 + lane * 4) = r1;
        *(float4v*)(xs + 512 + lane * 4) = r2;
        xs[768 + lane] = __float_as_uint(r3);

        // issue next iteration's global loads (in flight across layer chain)
        const int tbn = tb + STRIDE;
        if (tbn < tiles) {
            xp = x + (size_t)tbn * 208;
            r0 = *(const float4v*)(xp + lane * 4);
            r1 = *(const float4v*)(xp + 256 + lane * 4);
            r2 = *(const float4v*)(xp + 512 + lane * 4);
            r3 = xp[768 + lane];
        }

        // input-layer B fragments (stride-13 dword gather: conflict-free).
        // k slots 13..15 read neighbor x / zero pad: finite, A there is 0.
        half4v bf[T];
#pragma unroll
        for (int t = 0; t < T; ++t) {
            const unsigned* p = xs + t * 208 + col13k;
            bf[t] = pack4h(__uint_as_float(p[0]), __uint_as_float(p[1]),
                           __uint_as_float(p[2]), __uint_as_float(p[3]));
        }

        // ---- 31 layers, A/bias prefetched one ahead; bias rides in C ----
        half4v aC = lA[lane];          // layer 0
        float4v cC = lB[g];
#pragma unroll
        for (int L = 0; L < NL - 1; ++L) {
            const half4v aN = lA[(L + 1) * 64 + lane];
            const float4v cN = lB[(L + 1) * 4 + g];
            float4v d[T];
#pragma unroll
            for (int t = 0; t < T; ++t)
                d[t] = __builtin_amdgcn_mfma_f32_16x16x16f16(aC, bf[t], cC, 0, 0, 0);
#pragma unroll
            for (int t = 0; t < T; ++t)
                bf[t] = relu_pack4h(d[t]);
            aC = aN;
            cC = cN;
        }

        // output layer: W_out lives in row 0 only; y[n] = D[0][n]
#pragma unroll
        for (int t = 0; t < T; ++t) {
            float4v d = __builtin_amdgcn_mfma_f32_16x16x16f16(aC, bf[t], cC, 0, 0, 0);
            if (lane < 16) op[t * 16] = d[0];
        }
        op += (size_t)STRIDE * 16;
    }
}

extern "C" void kernel_launch(void* const* d_in, const int* in_sizes, int n_in,
                              void* d_out, int out_size, void* d_ws, size_t ws_size,
                              hipStream_t stream) {
    const float* x     = (const float*)d_in[0];
    const float* W_in  = (const float*)d_in[1];
    const float* b_in  = (const float*)d_in[2];
    const float* W_h   = (const float*)d_in[3];
    const float* b_h   = (const float*)d_in[4];
    const float* W_out = (const float*)d_in[5];
    const float* b_out = (const float*)d_in[6];
    float* out = (float*)d_out;

    const int tiles = out_size / 16;                       // 131072
    int blocks = (tiles + WPB * T - 1) / (WPB * T);
    if (blocks > NBLOCKS) blocks = NBLOCKS;
    mlp_kernel<<<blocks, TPB, 0, stream>>>(x, W_in, b_in, W_h, b_h, W_out, b_out,
                                           out, tiles);
}